// Round 1
// baseline (954.766 us; speedup 1.0000x reference)
//
#include <hip/hip_runtime.h>
#include <math.h>

// AtnConv (contextual attention) for B=2, H=W=64, C=128, k=3.
// y = Att2 @ X1 with Att2 the 9-point diagonal stencil of softmax rows.
// Workspace layout: buf1[L*L] f32, buf2[L*L] f32, invn[L], rowm[L], rowrz[L].
// Requires ws_size >= 2*L*L*4 + 3*L*4 = ~128 MB + 48 KB.

constexpr int Hh = 64;
constexpr int Ww = 64;
constexpr int CDIM = 128;
constexpr int LDIM = Hh * Ww;   // 4096

// ---------------------------------------------------------------- GEMM: D = X Xt
__global__ __launch_bounds__(256)
void k_gemm_d(const float* __restrict__ X, float* __restrict__ D) {
    constexpr int BM = 128, BN = 128, BK = 16;
    __shared__ float As[BK][BM + 4];
    __shared__ float Bs[BK][BN + 4];
    const int t  = threadIdx.x;
    const int bm = blockIdx.x * BM;
    const int bn = blockIdx.y * BN;
    const int tm = (t >> 4) << 3;     // 0..120
    const int tn = (t & 15) << 3;     // 0..120
    const int lr = t >> 1;            // 0..127
    const int lc = (t & 1) << 3;      // 0 or 8
    float acc[8][8] = {};
    for (int k0 = 0; k0 < CDIM; k0 += BK) {
        const float4 a0 = *(const float4*)(X + (size_t)(bm + lr) * CDIM + k0 + lc);
        const float4 a1 = *(const float4*)(X + (size_t)(bm + lr) * CDIM + k0 + lc + 4);
        const float4 b0 = *(const float4*)(X + (size_t)(bn + lr) * CDIM + k0 + lc);
        const float4 b1 = *(const float4*)(X + (size_t)(bn + lr) * CDIM + k0 + lc + 4);
        As[lc + 0][lr] = a0.x; As[lc + 1][lr] = a0.y; As[lc + 2][lr] = a0.z; As[lc + 3][lr] = a0.w;
        As[lc + 4][lr] = a1.x; As[lc + 5][lr] = a1.y; As[lc + 6][lr] = a1.z; As[lc + 7][lr] = a1.w;
        Bs[lc + 0][lr] = b0.x; Bs[lc + 1][lr] = b0.y; Bs[lc + 2][lr] = b0.z; Bs[lc + 3][lr] = b0.w;
        Bs[lc + 4][lr] = b1.x; Bs[lc + 5][lr] = b1.y; Bs[lc + 6][lr] = b1.z; Bs[lc + 7][lr] = b1.w;
        __syncthreads();
        #pragma unroll
        for (int k = 0; k < BK; ++k) {
            float a[8], b[8];
            *(float4*)(a)     = *(const float4*)(&As[k][tm]);
            *(float4*)(a + 4) = *(const float4*)(&As[k][tm + 4]);
            *(float4*)(b)     = *(const float4*)(&Bs[k][tn]);
            *(float4*)(b + 4) = *(const float4*)(&Bs[k][tn + 4]);
            #pragma unroll
            for (int i = 0; i < 8; ++i)
                #pragma unroll
                for (int j = 0; j < 8; ++j)
                    acc[i][j] = fmaf(a[i], b[j], acc[i][j]);
        }
        __syncthreads();
    }
    #pragma unroll
    for (int i = 0; i < 8; ++i) {
        float4 w0 = make_float4(acc[i][0], acc[i][1], acc[i][2], acc[i][3]);
        float4 w1 = make_float4(acc[i][4], acc[i][5], acc[i][6], acc[i][7]);
        *(float4*)(D + (size_t)(bm + tm + i) * LDIM + bn + tn)     = w0;
        *(float4*)(D + (size_t)(bm + tm + i) * LDIM + bn + tn + 4) = w1;
    }
}

// ------------------------------------------------- invn[l] = 1/max(sqrt(G[l,l]), eps)
__global__ void k_invnorm(const float* __restrict__ D, float* __restrict__ invn) {
    const int l = blockIdx.x * 256 + threadIdx.x;
    const int ly = l >> 6, lx = l & 63;
    float s = 0.f;
    #pragma unroll
    for (int ty = -1; ty <= 1; ++ty)
        #pragma unroll
        for (int tx = -1; tx <= 1; ++tx) {
            if ((unsigned)(ly + ty) < 64u && (unsigned)(lx + tx) < 64u) {
                const int q = l + ty * Ww + tx;
                s += D[(size_t)q * LDIM + q];
            }
        }
    invn[l] = 1.0f / fmaxf(sqrtf(s), 1e-4f);
}

// ------------------------------------------------- G[x,l] = sum_t D[x+t, l+t]
__global__ __launch_bounds__(256)
void k_gstencil(const float* __restrict__ D, float* __restrict__ G) {
    const int x = blockIdx.y;
    const int l = blockIdx.x * 256 + threadIdx.x;
    const int xy = x >> 6, xx = x & 63;
    const int ly = l >> 6, lx = l & 63;
    float s = 0.f;
    #pragma unroll
    for (int ty = -1; ty <= 1; ++ty)
        #pragma unroll
        for (int tx = -1; tx <= 1; ++tx) {
            if ((unsigned)(xy + ty) < 64u && (unsigned)(xx + tx) < 64u &&
                (unsigned)(ly + ty) < 64u && (unsigned)(lx + tx) < 64u) {
                const int off = ty * Ww + tx;
                s += D[(size_t)(x + off) * LDIM + (l + off)];
            }
        }
    G[(size_t)x * LDIM + l] = s;
}

// ------------------------- P[x,l] = (90/cnt_x)*invn[l]*sum_{s in N(x)} G[s,l]; row softmax stats
__global__ __launch_bounds__(256)
void k_pool_stats(const float* __restrict__ G, const float* __restrict__ invn,
                  float* __restrict__ P, float* __restrict__ rowm, float* __restrict__ rowrz) {
    const int x = blockIdx.x;
    const int xy = x >> 6, xx = x & 63;
    const int cnt = (1 + (xy > 0) + (xy < 63)) * (1 + (xx > 0) + (xx < 63));
    const float sc = 90.0f / (float)cnt;   // 10 * 9 / cnt
    const int t = threadIdx.x;
    float m = -1e30f, Z = 0.f;
    for (int chunk = 0; chunk < LDIM / 256; ++chunk) {
        const int l = chunk * 256 + t;
        float s = 0.f;
        #pragma unroll
        for (int ty = -1; ty <= 1; ++ty)
            #pragma unroll
            for (int tx = -1; tx <= 1; ++tx) {
                if ((unsigned)(xy + ty) < 64u && (unsigned)(xx + tx) < 64u)
                    s += G[(size_t)(x + ty * Ww + tx) * LDIM + l];
            }
        const float p = s * sc * invn[l];
        P[(size_t)x * LDIM + l] = p;
        const float nm = fmaxf(m, p);
        Z = Z * __expf(m - nm) + __expf(p - nm);
        m = nm;
    }
    __shared__ float sm[256], sz[256];
    sm[t] = m; sz[t] = Z;
    __syncthreads();
    for (int off = 128; off > 0; off >>= 1) {
        if (t < off) {
            const float m2 = sm[t + off], z2 = sz[t + off];
            const float nm = fmaxf(sm[t], m2);
            sz[t] = sz[t] * __expf(sm[t] - nm) + z2 * __expf(m2 - nm);
            sm[t] = nm;
        }
        __syncthreads();
    }
    if (t == 0) { rowm[x] = sm[0]; rowrz[x] = 1.0f / sz[0]; }
}

// --------------------- Att2[p,q] = sum_t exp(P[p+t,q+t]-m_{p+t})*rz_{p+t} (valid shifts)
__global__ __launch_bounds__(256)
void k_att2(const float* __restrict__ P, const float* __restrict__ rowm,
            const float* __restrict__ rowrz, float* __restrict__ A2) {
    const int p = blockIdx.y;
    const int q = blockIdx.x * 256 + threadIdx.x;
    const int py = p >> 6, px = p & 63;
    const int qy = q >> 6, qx = q & 63;
    float s = 0.f;
    #pragma unroll
    for (int ty = -1; ty <= 1; ++ty)
        #pragma unroll
        for (int tx = -1; tx <= 1; ++tx) {
            if ((unsigned)(py + ty) < 64u && (unsigned)(px + tx) < 64u &&
                (unsigned)(qy + ty) < 64u && (unsigned)(qx + tx) < 64u) {
                const int off = ty * Ww + tx;
                const int u = p + off;
                s += __expf(P[(size_t)u * LDIM + (q + off)] - rowm[u]) * rowrz[u];
            }
        }
    A2[(size_t)p * LDIM + q] = s;
}

// ---------------------------------------------- Y += A2 @ X1  (split-K, atomic f32)
__global__ __launch_bounds__(256)
void k_gemm_y(const float* __restrict__ A2, const float* __restrict__ X1v,
              float* __restrict__ Y) {
    constexpr int BM = 64, BK = 32, KS = 512;
    __shared__ float As[BK][BM + 4];
    __shared__ float Bs[BK][CDIM + 4];
    const int t = threadIdx.x;
    const int bm = blockIdx.x * BM;
    const int kbase = blockIdx.y * KS;
    const int tm = (t >> 5) << 3;   // 0..56
    const int tn = (t & 31) << 2;   // 0..124
    const int ar = t >> 2, ac = (t & 3) << 3;
    const int br = t >> 3, bc = (t & 7) << 4;
    float acc[8][4] = {};
    for (int ks = 0; ks < KS; ks += BK) {
        const int k0 = kbase + ks;
        const float4 a0 = *(const float4*)(A2 + (size_t)(bm + ar) * LDIM + k0 + ac);
        const float4 a1 = *(const float4*)(A2 + (size_t)(bm + ar) * LDIM + k0 + ac + 4);
        As[ac + 0][ar] = a0.x; As[ac + 1][ar] = a0.y; As[ac + 2][ar] = a0.z; As[ac + 3][ar] = a0.w;
        As[ac + 4][ar] = a1.x; As[ac + 5][ar] = a1.y; As[ac + 6][ar] = a1.z; As[ac + 7][ar] = a1.w;
        const float* src = X1v + (size_t)(k0 + br) * CDIM + bc;
        *(float4*)(&Bs[br][bc])      = *(const float4*)(src);
        *(float4*)(&Bs[br][bc + 4])  = *(const float4*)(src + 4);
        *(float4*)(&Bs[br][bc + 8])  = *(const float4*)(src + 8);
        *(float4*)(&Bs[br][bc + 12]) = *(const float4*)(src + 12);
        __syncthreads();
        #pragma unroll
        for (int k = 0; k < BK; ++k) {
            float a[8], b[4];
            *(float4*)(a)     = *(const float4*)(&As[k][tm]);
            *(float4*)(a + 4) = *(const float4*)(&As[k][tm + 4]);
            *(float4*)(b)     = *(const float4*)(&Bs[k][tn]);
            #pragma unroll
            for (int i = 0; i < 8; ++i)
                #pragma unroll
                for (int j = 0; j < 4; ++j)
                    acc[i][j] = fmaf(a[i], b[j], acc[i][j]);
        }
        __syncthreads();
    }
    #pragma unroll
    for (int i = 0; i < 8; ++i)
        #pragma unroll
        for (int j = 0; j < 4; ++j)
            atomicAdd(Y + (size_t)(bm + tm + i) * CDIM + tn + j, acc[i][j]);
}

extern "C" void kernel_launch(void* const* d_in, const int* in_sizes, int n_in,
                              void* d_out, int out_size, void* d_ws, size_t ws_size,
                              hipStream_t stream) {
    const float* x1 = (const float*)d_in[0];
    const float* x2 = (const float*)d_in[1];
    // d_in[2] (mask) only updates internal state in the reference; unused for y.
    float* out = (float*)d_out;

    const size_t MATB = (size_t)LDIM * LDIM * sizeof(float);   // 64 MB
    char* ws = (char*)d_ws;
    float* buf1  = (float*)ws;                   // D, then P
    float* buf2  = (float*)(ws + MATB);          // G, then Att2
    float* invn  = (float*)(ws + 2 * MATB);
    float* rowm  = invn + LDIM;
    float* rowrz = rowm + LDIM;

    const int B = in_sizes[0] / (LDIM * CDIM);   // 2

    hipMemsetAsync(d_out, 0, (size_t)out_size * sizeof(float), stream);

    for (int b = 0; b < B; ++b) {
        const float* X2b = x2 + (size_t)b * LDIM * CDIM;
        const float* X1b = x1 + (size_t)b * LDIM * CDIM;
        float* Yb = out + (size_t)b * LDIM * CDIM;

        k_gemm_d  <<<dim3(LDIM / 128, LDIM / 128), 256, 0, stream>>>(X2b, buf1);
        k_invnorm <<<LDIM / 256, 256, 0, stream>>>(buf1, invn);
        k_gstencil<<<dim3(LDIM / 256, LDIM), 256, 0, stream>>>(buf1, buf2);
        k_pool_stats<<<LDIM, 256, 0, stream>>>(buf2, invn, buf1, rowm, rowrz);
        k_att2    <<<dim3(LDIM / 256, LDIM), 256, 0, stream>>>(buf1, rowm, rowrz, buf2);
        k_gemm_y  <<<dim3(LDIM / 64, LDIM / 512), 256, 0, stream>>>(buf2, X1b, Yb);
    }
}